// Round 7
// baseline (530.927 us; speedup 1.0000x reference)
//
#include <hip/hip_runtime.h>

#define L 2048
#define CIN 16
#define GROUPS 4
#define NEG_INF  -1000000000.0f
#define POS_THRESH -100000000.0f

// ---------------------------------------------------------------------------
// Kernel A: sparsemax tau, one wave per row, FIXED-COST exact algorithm.
// (unchanged — proven)
// ---------------------------------------------------------------------------
__global__ __launch_bounds__(256) void tau_kernel(const float* __restrict__ scores,
                                                  float* __restrict__ tau_out) {
    const int wid  = (blockIdx.x << 2) + (threadIdx.x >> 6);
    const int lane = threadIdx.x & 63;
    const int ws   = threadIdx.x >> 6;            // wave slot in block
    const int ch   = wid >> 11;
    const int row  = wid & 2047;
    const int n    = row + 1;
    const float* zrow = scores + ((size_t)ch * L + row) * L;

    float v[32];
    float m = NEG_INF;
#pragma unroll
    for (int j = 0; j < 8; ++j) {
        int c4 = lane + (j << 6);
        int c  = c4 << 2;
        float4 z = make_float4(NEG_INF, NEG_INF, NEG_INF, NEG_INF);
        if (c < n) z = *((const float4*)zrow + c4);
        v[4*j+0] = (c + 0 < n) ? z.x : NEG_INF;
        v[4*j+1] = (c + 1 < n) ? z.y : NEG_INF;
        v[4*j+2] = (c + 2 < n) ? z.z : NEG_INF;
        v[4*j+3] = (c + 3 < n) ? z.w : NEG_INF;
        m = fmaxf(m, fmaxf(fmaxf(v[4*j+0], v[4*j+1]), fmaxf(v[4*j+2], v[4*j+3])));
    }
#pragma unroll
    for (int d = 32; d; d >>= 1) m = fmaxf(m, __shfl_xor(m, d, 64));

    const float thr = m - 1.0f;

    // ---- compact candidates {v > thr} into per-wave LDS buffer ----
    __shared__ float buf[4][64];
    int base = 0;
#pragma unroll
    for (int j = 0; j < 32; ++j) {
        bool p = v[j] > thr;
        unsigned long long mask = __ballot(p);
        if (mask) {
            if (p) {
                int pos = __builtin_amdgcn_mbcnt_lo((unsigned)mask, 0);
                pos = __builtin_amdgcn_mbcnt_hi((unsigned)(mask >> 32), pos);
                pos += base;
                if (pos < 64) buf[ws][pos] = v[j];
            }
            base += __popcll(mask);
        }
    }
    __syncthreads();
    const int cnt = base;

    float tau;
    if (cnt <= 64) {
        float x = (lane < cnt) ? buf[ws][lane] : NEG_INF;
        // bitonic sort, descending across 64 lanes
#pragma unroll
        for (int k = 2; k <= 64; k <<= 1) {
#pragma unroll
            for (int j = k >> 1; j > 0; j >>= 1) {
                float p = __shfl_xor(x, j, 64);
                bool desc    = ((lane & k) == 0);
                bool earlier = ((lane & j) == 0);
                float mx = fmaxf(x, p), mn = fminf(x, p);
                x = (desc == earlier) ? mx : mn;
            }
        }
        // inclusive prefix sum
        float csum = x;
#pragma unroll
        for (int d = 1; d < 64; d <<= 1) {
            float y = __shfl_up(csum, d, 64);
            if (lane >= d) csum += y;
        }
        bool cond = (1.0f + (float)(lane + 1) * x > csum) && (x > POS_THRESH);
        unsigned long long cmask = __ballot(cond);
        int k = (int)__popcll(cmask);             // k >= 1 always (max elem qualifies)
        float ck = __shfl(csum, k - 1, 64);
        tau = (ck - 1.0f) / (float)k;
    } else {
        // Michelot fallback — correctness safety net only.
        tau = thr;
        int k_prev = -1;
        for (int it = 0; it < 64; ++it) {
            float S = 0.0f, Kf = 0.0f;
#pragma unroll
            for (int j = 0; j < 32; ++j)
                if (v[j] > tau) { S += v[j]; Kf += 1.0f; }
#pragma unroll
            for (int d = 32; d; d >>= 1) {
                S  += __shfl_xor(S,  d, 64);
                Kf += __shfl_xor(Kf, d, 64);
            }
            int K = (int)Kf;
            if (K == k_prev) break;
            tau = (S - 1.0f) / Kf;
            k_prev = K;
        }
    }
    if (lane == 0) tau_out[ch * L + row] = tau;
}

// ---------------------------------------------------------------------------
// Kernel B: grouped 3x3 conv over on-the-fly probs = max(score - tau, 0).
// Round-2 staging/layout (TC=64, issue-all-then-write, LDS P[4][18][68],
// halos at [64]/[67], __launch_bounds__(256,8) -> 8 blocks/CU).
// Compute: wave -> 4 OUTPUT ROWS (not oc); each lane computes all 4 oc for
// 1 row x 4 cols, so each LDS window feeds 4x the FMAs: windows/lane 24->12,
// per-wave DS ~672 -> ~336 cy (DS wall ~36us < ~68us HBM term).
// Defensive codegen: no local aggregates in the FMA nest (explicit q0/q1/q2,
// named weight scalars) — avoids any scratch-allocation hazard.
// ---------------------------------------------------------------------------
#define TR 16
#define TC 64
#define HR 18
#define PST 68

struct W6 { float l, m0, m1, m2, m3, r; };

__global__ __launch_bounds__(256, 8) void conv_kernel(const float* __restrict__ scores,
                                                      const float* __restrict__ tau,
                                                      const float* __restrict__ weight,
                                                      const float* __restrict__ bias,
                                                      float* __restrict__ out) {
    const int c0 = blockIdx.x * TC;
    const int r0 = blockIdx.y * TR;
    const int g  = blockIdx.z;
    const int t  = threadIdx.x;

    // Fully-dead tile: vectorized zero-fill, no loads.
    if (c0 > r0 + TR - 1) {
        const float4 z4 = make_float4(0.f, 0.f, 0.f, 0.f);
#pragma unroll
        for (int jj = 0; jj < 4; ++jj) {
            int idx = t + (jj << 8);              // 0..1023
            int c4  = idx & 15;
            int r   = (idx >> 4) & 15;
            int o   = idx >> 8;
            float4* p = (float4*)(out + (((size_t)((g << 2) + o) * L + (r0 + r)) * L + c0)) + c4;
            *p = z4;
        }
        return;
    }

    __shared__ __align__(16) float P[4][HR][PST];

    const bool interior = (c0 >= 1) && (c0 + TC + 1 <= r0) && (r0 + TR <= L - 1);

    const float* sbase = scores + (size_t)(g << 2) * L * L;
    const float* tbase = tau + (g << 2) * L;

    // main quads: 4 ic x 18 hr x 16 c4 = 1152, flat layout [hr][ic][c4]
    float4 zr[5];
    float  tvr[5];

    if (interior) {
        // ---- issue ALL global loads first ----
#pragma unroll
        for (int jj = 0; jj < 5; ++jj) {
            int idx = t + (jj << 8);
            if (idx < 1152) {
                int hr = idx >> 6, ic = (idx >> 4) & 3, c4 = idx & 15;
                int r  = r0 - 1 + hr;
                zr[jj]  = *((const float4*)(sbase + (size_t)ic * L * L + (size_t)r * L + c0) + c4);
                tvr[jj] = tbase[ic * L + r];
            }
        }
        float hv = 0.f;
        int hic = 0, hhr = 0, hside = 0;
        if (t < 144) {
            hside = t & 1;
            int j = t >> 1;
            hic = j / HR; hhr = j - hic * HR;
            int r = r0 - 1 + hhr;
            int c = hside ? (c0 + TC) : (c0 - 1);
            hv = fmaxf(sbase[(size_t)hic * L * L + (size_t)r * L + c] - tbase[hic * L + r], 0.f);
        }
        // ---- transform + LDS writes ----
#pragma unroll
        for (int jj = 0; jj < 5; ++jj) {
            int idx = t + (jj << 8);
            if (idx < 1152) {
                int hr = idx >> 6, ic = (idx >> 4) & 3, c4 = idx & 15;
                float tv = tvr[jj];
                float4 z = zr[jj];
                float4 val;
                val.x = fmaxf(z.x - tv, 0.f);
                val.y = fmaxf(z.y - tv, 0.f);
                val.z = fmaxf(z.z - tv, 0.f);
                val.w = fmaxf(z.w - tv, 0.f);
                *((float4*)&P[ic][hr][c4 << 2]) = val;
            }
        }
        if (t < 144) P[hic][hhr][hside ? TC : 67] = hv;
    } else {
        // ---- checked staging (boundary / diagonal tiles) ----
#pragma unroll
        for (int jj = 0; jj < 5; ++jj) {
            int idx = t + (jj << 8);
            zr[jj] = make_float4(0.f, 0.f, 0.f, 0.f);
            tvr[jj] = 0.f;
            if (idx < 1152) {
                int hr = idx >> 6, ic = (idx >> 4) & 3, c4 = idx & 15;
                int r  = r0 - 1 + hr;
                int cb = c0 + (c4 << 2);
                if (r >= 0 && r < L && cb <= r) {
                    zr[jj]  = *((const float4*)(sbase + (size_t)ic * L * L + (size_t)r * L) + (cb >> 2));
                    tvr[jj] = tbase[ic * L + r];
                }
            }
        }
        float hv = 0.f;
        int hic = 0, hhr = 0, hside = 0;
        if (t < 144) {
            hside = t & 1;
            int j = t >> 1;
            hic = j / HR; hhr = j - hic * HR;
            int r = r0 - 1 + hhr;
            int c = hside ? (c0 + TC) : (c0 - 1);
            if (r >= 0 && r < L && c >= 0 && c <= r)
                hv = fmaxf(sbase[(size_t)hic * L * L + (size_t)r * L + c] - tbase[hic * L + r], 0.f);
        }
#pragma unroll
        for (int jj = 0; jj < 5; ++jj) {
            int idx = t + (jj << 8);
            if (idx < 1152) {
                int hr = idx >> 6, ic = (idx >> 4) & 3, c4 = idx & 15;
                int r  = r0 - 1 + hr;
                int cb = c0 + (c4 << 2);
                float tv = tvr[jj];
                float4 z = zr[jj];
                float4 val = make_float4(0.f, 0.f, 0.f, 0.f);
                if (r >= 0 && r < L && cb <= r) {
                    val.x = fmaxf(z.x - tv, 0.f);
                    val.y = (cb + 1 <= r) ? fmaxf(z.y - tv, 0.f) : 0.f;
                    val.z = (cb + 2 <= r) ? fmaxf(z.z - tv, 0.f) : 0.f;
                    val.w = (cb + 3 <= r) ? fmaxf(z.w - tv, 0.f) : 0.f;
                }
                *((float4*)&P[ic][hr][c4 << 2]) = val;
            }
        }
        if (t < 144) P[hic][hhr][hside ? TC : 67] = hv;
    }
    __syncthreads();

    // ---- compute: wave = 4 output rows; lane = (row-in-wave, col quad);
    //      each lane computes all 4 oc for its 1 row x 4 cols. ----
    const int w4   = t >> 6;                       // wave 0..3
    const int lane = t & 63;
    const int col4 = lane & 15;
    const int rloc = lane >> 4;                    // row within wave quad 0..3
    const int ro   = (w4 << 2) + rloc;             // output row within tile 0..15
    const int obase = g << 2;
    const int cb   = c0 + (col4 << 2);
    const int li   = col4 ? ((col4 << 2) - 2) : 66;   // left b64 idx (use .y)
    const int ri   = (col4 << 2) + 4;                 // right b64 idx (use .x)

    auto ldwin = [&](int ic, int hr) -> W6 {
        const float* rp = &P[ic][hr][0];
        float4 M  = *(const float4*)(rp + (col4 << 2));
        float2 Lv = *(const float2*)(rp + li);
        float2 Rv = *(const float2*)(rp + ri);
        W6 q; q.l = Lv.y; q.m0 = M.x; q.m1 = M.y; q.m2 = M.z; q.m3 = M.w; q.r = Rv.x;
        return q;
    };

    float4 acc[4];
#pragma unroll
    for (int oc = 0; oc < 4; ++oc) {
        float bb = bias[obase + oc];
        acc[oc] = make_float4(bb, bb, bb, bb);
    }

#define ROWFMA(q, wa, wb, wc, A)                                           \
    A.x = fmaf(q.l,  wa, fmaf(q.m0, wb, fmaf(q.m1, wc, A.x)));             \
    A.y = fmaf(q.m0, wa, fmaf(q.m1, wb, fmaf(q.m2, wc, A.y)));             \
    A.z = fmaf(q.m1, wa, fmaf(q.m2, wb, fmaf(q.m3, wc, A.z)));             \
    A.w = fmaf(q.m2, wa, fmaf(q.m3, wb, fmaf(q.r,  wc, A.w)));

#pragma unroll
    for (int ic = 0; ic < 4; ++ic) {
        // windows for output row ro: staged rows ro, ro+1, ro+2
        W6 q0 = ldwin(ic, ro);
        W6 q1 = ldwin(ic, ro + 1);
        W6 q2 = ldwin(ic, ro + 2);
#pragma unroll
        for (int oc = 0; oc < 4; ++oc) {
            const float* wp = weight + (((obase + oc) << 2) + ic) * 9;  // uniform -> s_load
            const float w00 = wp[0], w01 = wp[1], w02 = wp[2];
            const float w10 = wp[3], w11 = wp[4], w12 = wp[5];
            const float w20 = wp[6], w21 = wp[7], w22 = wp[8];
            ROWFMA(q0, w00, w01, w02, acc[oc])
            ROWFMA(q1, w10, w11, w12, acc[oc])
            ROWFMA(q2, w20, w21, w22, acc[oc])
        }
    }
#undef ROWFMA

    const int r_out = r0 + ro;
    if (interior) {
#pragma unroll
        for (int oc = 0; oc < 4; ++oc) {
            float* outp = out + ((size_t)(obase + oc) * L + r_out) * L + cb;
            *(float4*)outp = acc[oc];
        }
    } else {
#pragma unroll
        for (int oc = 0; oc < 4; ++oc) {
            float4 res;
            res.x = (cb     <= r_out) ? acc[oc].x : 0.f;
            res.y = (cb + 1 <= r_out) ? acc[oc].y : 0.f;
            res.z = (cb + 2 <= r_out) ? acc[oc].z : 0.f;
            res.w = (cb + 3 <= r_out) ? acc[oc].w : 0.f;
            float* outp = out + ((size_t)(obase + oc) * L + r_out) * L + cb;
            *(float4*)outp = res;
        }
    }
}

extern "C" void kernel_launch(void* const* d_in, const int* in_sizes, int n_in,
                              void* d_out, int out_size, void* d_ws, size_t ws_size,
                              hipStream_t stream) {
    const float* scores = (const float*)d_in[0];
    const float* weight = (const float*)d_in[1];
    const float* bias   = (const float*)d_in[2];
    float* out = (float*)d_out;
    float* tau = (float*)d_ws;                 // 16*2048 floats = 128 KB

    tau_kernel<<<(CIN * L) / 4, 256, 0, stream>>>(scores, tau);

    dim3 gridB(L / TC, L / TR, GROUPS);
    conv_kernel<<<gridB, 256, 0, stream>>>(scores, tau, weight, bias, out);
}

// Round 8
// 486.018 us; speedup vs baseline: 1.0924x; 1.0924x over previous
//
#include <hip/hip_runtime.h>

#define L 2048
#define CIN 16
#define GROUPS 4
#define NEG_INF  -1000000000.0f
#define POS_THRESH -100000000.0f

// ---------------------------------------------------------------------------
// Kernel A: sparsemax tau, one wave per row, FIXED-COST exact algorithm.
// (unchanged — proven)
// ---------------------------------------------------------------------------
__global__ __launch_bounds__(256) void tau_kernel(const float* __restrict__ scores,
                                                  float* __restrict__ tau_out) {
    const int wid  = (blockIdx.x << 2) + (threadIdx.x >> 6);
    const int lane = threadIdx.x & 63;
    const int ws   = threadIdx.x >> 6;            // wave slot in block
    const int ch   = wid >> 11;
    const int row  = wid & 2047;
    const int n    = row + 1;
    const float* zrow = scores + ((size_t)ch * L + row) * L;

    float v[32];
    float m = NEG_INF;
#pragma unroll
    for (int j = 0; j < 8; ++j) {
        int c4 = lane + (j << 6);
        int c  = c4 << 2;
        float4 z = make_float4(NEG_INF, NEG_INF, NEG_INF, NEG_INF);
        if (c < n) z = *((const float4*)zrow + c4);
        v[4*j+0] = (c + 0 < n) ? z.x : NEG_INF;
        v[4*j+1] = (c + 1 < n) ? z.y : NEG_INF;
        v[4*j+2] = (c + 2 < n) ? z.z : NEG_INF;
        v[4*j+3] = (c + 3 < n) ? z.w : NEG_INF;
        m = fmaxf(m, fmaxf(fmaxf(v[4*j+0], v[4*j+1]), fmaxf(v[4*j+2], v[4*j+3])));
    }
#pragma unroll
    for (int d = 32; d; d >>= 1) m = fmaxf(m, __shfl_xor(m, d, 64));

    const float thr = m - 1.0f;

    // ---- compact candidates {v > thr} into per-wave LDS buffer ----
    __shared__ float buf[4][64];
    int base = 0;
#pragma unroll
    for (int j = 0; j < 32; ++j) {
        bool p = v[j] > thr;
        unsigned long long mask = __ballot(p);
        if (mask) {
            if (p) {
                int pos = __builtin_amdgcn_mbcnt_lo((unsigned)mask, 0);
                pos = __builtin_amdgcn_mbcnt_hi((unsigned)(mask >> 32), pos);
                pos += base;
                if (pos < 64) buf[ws][pos] = v[j];
            }
            base += __popcll(mask);
        }
    }
    __syncthreads();
    const int cnt = base;

    float tau;
    if (cnt <= 64) {
        float x = (lane < cnt) ? buf[ws][lane] : NEG_INF;
        // bitonic sort, descending across 64 lanes
#pragma unroll
        for (int k = 2; k <= 64; k <<= 1) {
#pragma unroll
            for (int j = k >> 1; j > 0; j >>= 1) {
                float p = __shfl_xor(x, j, 64);
                bool desc    = ((lane & k) == 0);
                bool earlier = ((lane & j) == 0);
                float mx = fmaxf(x, p), mn = fminf(x, p);
                x = (desc == earlier) ? mx : mn;
            }
        }
        // inclusive prefix sum
        float csum = x;
#pragma unroll
        for (int d = 1; d < 64; d <<= 1) {
            float y = __shfl_up(csum, d, 64);
            if (lane >= d) csum += y;
        }
        bool cond = (1.0f + (float)(lane + 1) * x > csum) && (x > POS_THRESH);
        unsigned long long cmask = __ballot(cond);
        int k = (int)__popcll(cmask);             // k >= 1 always (max elem qualifies)
        float ck = __shfl(csum, k - 1, 64);
        tau = (ck - 1.0f) / (float)k;
    } else {
        // Michelot fallback — correctness safety net only.
        tau = thr;
        int k_prev = -1;
        for (int it = 0; it < 64; ++it) {
            float S = 0.0f, Kf = 0.0f;
#pragma unroll
            for (int j = 0; j < 32; ++j)
                if (v[j] > tau) { S += v[j]; Kf += 1.0f; }
#pragma unroll
            for (int d = 32; d; d >>= 1) {
                S  += __shfl_xor(S,  d, 64);
                Kf += __shfl_xor(Kf, d, 64);
            }
            int K = (int)Kf;
            if (K == k_prev) break;
            tau = (S - 1.0f) / Kf;
            k_prev = K;
        }
    }
    if (lane == 0) tau_out[ch * L + row] = tau;
}

// ---------------------------------------------------------------------------
// Kernel B: grouped 3x3 conv over on-the-fly probs = max(score - tau, 0).
// Round-2 staging/layout (TC=64, issue-all-then-write, LDS P[4][18][68],
// halos at [64]/[67]).  Compute: wave -> 4 OUTPUT ROWS; each lane computes
// all 4 oc for 1 row x 4 cols (windows/lane 24->12 vs wave-per-oc).
//
// Round-7 post-mortem fixes:
//  * __launch_bounds__(256, 4): with 19.5 KB LDS the block is ALREADY capped
//    at 8 blocks/CU, so the (256,8) bound only pressured the allocator into
//    a 32-VGPR + scratch-spill solution (FETCH/WRITE +134 MB, conv 168us).
//    (256,4) raises the cap; any allocation <=64 VGPR still runs 8 blocks/CU.
//  * Weights forced to SGPRs via readfirstlane (wave-uniform by construction)
//    -> peak VGPR demand ~45, making a clean <=64-reg allocation natural.
// ---------------------------------------------------------------------------
#define TR 16
#define TC 64
#define HR 18
#define PST 68

struct W6 { float l, m0, m1, m2, m3, r; };

__device__ __forceinline__ float rfl(float x) {
    return __builtin_bit_cast(float,
        __builtin_amdgcn_readfirstlane(__builtin_bit_cast(int, x)));
}

__global__ __launch_bounds__(256, 4) void conv_kernel(const float* __restrict__ scores,
                                                      const float* __restrict__ tau,
                                                      const float* __restrict__ weight,
                                                      const float* __restrict__ bias,
                                                      float* __restrict__ out) {
    const int c0 = blockIdx.x * TC;
    const int r0 = blockIdx.y * TR;
    const int g  = blockIdx.z;
    const int t  = threadIdx.x;

    // Fully-dead tile: vectorized zero-fill, no loads.
    if (c0 > r0 + TR - 1) {
        const float4 z4 = make_float4(0.f, 0.f, 0.f, 0.f);
#pragma unroll
        for (int jj = 0; jj < 4; ++jj) {
            int idx = t + (jj << 8);              // 0..1023
            int c4  = idx & 15;
            int r   = (idx >> 4) & 15;
            int o   = idx >> 8;
            float4* p = (float4*)(out + (((size_t)((g << 2) + o) * L + (r0 + r)) * L + c0)) + c4;
            *p = z4;
        }
        return;
    }

    __shared__ __align__(16) float P[4][HR][PST];

    const bool interior = (c0 >= 1) && (c0 + TC + 1 <= r0) && (r0 + TR <= L - 1);

    const float* sbase = scores + (size_t)(g << 2) * L * L;
    const float* tbase = tau + (g << 2) * L;

    // main quads: 4 ic x 18 hr x 16 c4 = 1152, flat layout [hr][ic][c4]
    float4 zr[5];
    float  tvr[5];

    if (interior) {
        // ---- issue ALL global loads first ----
#pragma unroll
        for (int jj = 0; jj < 5; ++jj) {
            int idx = t + (jj << 8);
            if (idx < 1152) {
                int hr = idx >> 6, ic = (idx >> 4) & 3, c4 = idx & 15;
                int r  = r0 - 1 + hr;
                zr[jj]  = *((const float4*)(sbase + (size_t)ic * L * L + (size_t)r * L + c0) + c4);
                tvr[jj] = tbase[ic * L + r];
            }
        }
        float hv = 0.f;
        int hic = 0, hhr = 0, hside = 0;
        if (t < 144) {
            hside = t & 1;
            int j = t >> 1;
            hic = j / HR; hhr = j - hic * HR;
            int r = r0 - 1 + hhr;
            int c = hside ? (c0 + TC) : (c0 - 1);
            hv = fmaxf(sbase[(size_t)hic * L * L + (size_t)r * L + c] - tbase[hic * L + r], 0.f);
        }
        // ---- transform + LDS writes ----
#pragma unroll
        for (int jj = 0; jj < 5; ++jj) {
            int idx = t + (jj << 8);
            if (idx < 1152) {
                int hr = idx >> 6, ic = (idx >> 4) & 3, c4 = idx & 15;
                float tv = tvr[jj];
                float4 z = zr[jj];
                float4 val;
                val.x = fmaxf(z.x - tv, 0.f);
                val.y = fmaxf(z.y - tv, 0.f);
                val.z = fmaxf(z.z - tv, 0.f);
                val.w = fmaxf(z.w - tv, 0.f);
                *((float4*)&P[ic][hr][c4 << 2]) = val;
            }
        }
        if (t < 144) P[hic][hhr][hside ? TC : 67] = hv;
    } else {
        // ---- checked staging (boundary / diagonal tiles) ----
#pragma unroll
        for (int jj = 0; jj < 5; ++jj) {
            int idx = t + (jj << 8);
            zr[jj] = make_float4(0.f, 0.f, 0.f, 0.f);
            tvr[jj] = 0.f;
            if (idx < 1152) {
                int hr = idx >> 6, ic = (idx >> 4) & 3, c4 = idx & 15;
                int r  = r0 - 1 + hr;
                int cb = c0 + (c4 << 2);
                if (r >= 0 && r < L && cb <= r) {
                    zr[jj]  = *((const float4*)(sbase + (size_t)ic * L * L + (size_t)r * L) + (cb >> 2));
                    tvr[jj] = tbase[ic * L + r];
                }
            }
        }
        float hv = 0.f;
        int hic = 0, hhr = 0, hside = 0;
        if (t < 144) {
            hside = t & 1;
            int j = t >> 1;
            hic = j / HR; hhr = j - hic * HR;
            int r = r0 - 1 + hhr;
            int c = hside ? (c0 + TC) : (c0 - 1);
            if (r >= 0 && r < L && c >= 0 && c <= r)
                hv = fmaxf(sbase[(size_t)hic * L * L + (size_t)r * L + c] - tbase[hic * L + r], 0.f);
        }
#pragma unroll
        for (int jj = 0; jj < 5; ++jj) {
            int idx = t + (jj << 8);
            if (idx < 1152) {
                int hr = idx >> 6, ic = (idx >> 4) & 3, c4 = idx & 15;
                int r  = r0 - 1 + hr;
                int cb = c0 + (c4 << 2);
                float tv = tvr[jj];
                float4 z = zr[jj];
                float4 val = make_float4(0.f, 0.f, 0.f, 0.f);
                if (r >= 0 && r < L && cb <= r) {
                    val.x = fmaxf(z.x - tv, 0.f);
                    val.y = (cb + 1 <= r) ? fmaxf(z.y - tv, 0.f) : 0.f;
                    val.z = (cb + 2 <= r) ? fmaxf(z.z - tv, 0.f) : 0.f;
                    val.w = (cb + 3 <= r) ? fmaxf(z.w - tv, 0.f) : 0.f;
                }
                *((float4*)&P[ic][hr][c4 << 2]) = val;
            }
        }
        if (t < 144) P[hic][hhr][hside ? TC : 67] = hv;
    }
    __syncthreads();

    // ---- compute: wave = 4 output rows; lane = (row-in-wave, col quad);
    //      each lane computes all 4 oc for its 1 row x 4 cols. ----
    const int w4   = t >> 6;                       // wave 0..3
    const int lane = t & 63;
    const int col4 = lane & 15;
    const int rloc = lane >> 4;                    // row within wave quad 0..3
    const int ro   = (w4 << 2) + rloc;             // output row within tile 0..15
    const int obase = g << 2;
    const int cb   = c0 + (col4 << 2);
    const int li   = col4 ? ((col4 << 2) - 2) : 66;   // left b64 idx (use .y)
    const int ri   = (col4 << 2) + 4;                 // right b64 idx (use .x)

    auto ldwin = [&](int ic, int hr) -> W6 {
        const float* rp = &P[ic][hr][0];
        float4 M  = *(const float4*)(rp + (col4 << 2));
        float2 Lv = *(const float2*)(rp + li);
        float2 Rv = *(const float2*)(rp + ri);
        W6 q; q.l = Lv.y; q.m0 = M.x; q.m1 = M.y; q.m2 = M.z; q.m3 = M.w; q.r = Rv.x;
        return q;
    };

    float4 acc[4];
#pragma unroll
    for (int oc = 0; oc < 4; ++oc) {
        float bb = rfl(bias[obase + oc]);
        acc[oc] = make_float4(bb, bb, bb, bb);
    }

#define ROWFMA(q, wa, wb, wc, A)                                           \
    A.x = fmaf(q.l,  wa, fmaf(q.m0, wb, fmaf(q.m1, wc, A.x)));             \
    A.y = fmaf(q.m0, wa, fmaf(q.m1, wb, fmaf(q.m2, wc, A.y)));             \
    A.z = fmaf(q.m1, wa, fmaf(q.m2, wb, fmaf(q.m3, wc, A.z)));             \
    A.w = fmaf(q.m2, wa, fmaf(q.m3, wb, fmaf(q.r,  wc, A.w)));

#pragma unroll
    for (int ic = 0; ic < 4; ++ic) {
        // windows for output row ro: staged rows ro, ro+1, ro+2
        W6 q0 = ldwin(ic, ro);
        W6 q1 = ldwin(ic, ro + 1);
        W6 q2 = ldwin(ic, ro + 2);
#pragma unroll
        for (int oc = 0; oc < 4; ++oc) {
            const float* wp = weight + (((obase + oc) << 2) + ic) * 9;  // wave-uniform
            const float w00 = rfl(wp[0]), w01 = rfl(wp[1]), w02 = rfl(wp[2]);
            const float w10 = rfl(wp[3]), w11 = rfl(wp[4]), w12 = rfl(wp[5]);
            const float w20 = rfl(wp[6]), w21 = rfl(wp[7]), w22 = rfl(wp[8]);
            ROWFMA(q0, w00, w01, w02, acc[oc])
            ROWFMA(q1, w10, w11, w12, acc[oc])
            ROWFMA(q2, w20, w21, w22, acc[oc])
        }
    }
#undef ROWFMA

    const int r_out = r0 + ro;
    if (interior) {
#pragma unroll
        for (int oc = 0; oc < 4; ++oc) {
            float* outp = out + ((size_t)(obase + oc) * L + r_out) * L + cb;
            *(float4*)outp = acc[oc];
        }
    } else {
#pragma unroll
        for (int oc = 0; oc < 4; ++oc) {
            float4 res;
            res.x = (cb     <= r_out) ? acc[oc].x : 0.f;
            res.y = (cb + 1 <= r_out) ? acc[oc].y : 0.f;
            res.z = (cb + 2 <= r_out) ? acc[oc].z : 0.f;
            res.w = (cb + 3 <= r_out) ? acc[oc].w : 0.f;
            float* outp = out + ((size_t)(obase + oc) * L + r_out) * L + cb;
            *(float4*)outp = res;
        }
    }
}

extern "C" void kernel_launch(void* const* d_in, const int* in_sizes, int n_in,
                              void* d_out, int out_size, void* d_ws, size_t ws_size,
                              hipStream_t stream) {
    const float* scores = (const float*)d_in[0];
    const float* weight = (const float*)d_in[1];
    const float* bias   = (const float*)d_in[2];
    float* out = (float*)d_out;
    float* tau = (float*)d_ws;                 // 16*2048 floats = 128 KB

    tau_kernel<<<(CIN * L) / 4, 256, 0, stream>>>(scores, tau);

    dim3 gridB(L / TC, L / TR, GROUPS);
    conv_kernel<<<gridB, 256, 0, stream>>>(scores, tau, weight, bias, out);
}